// Round 8
// baseline (496.151 us; speedup 1.0000x reference)
//
#include <hip/hip_runtime.h>
#include <math.h>

// Problem constants (from reference setup_inputs): B=64, T=2048, D=768, fp32.
#define B_ 64
#define T_ 2048
#define D_ 768
#define D4_ 192           // float4 per frame (3 KB/frame)
#define CHUNK_ 64         // frames per task -> 192 KB contiguous per task
#define NCHUNK_ 32        // chunks per row
#define TASKS_ (B_ * NCHUNK_)   // 2048
#define GRID_P_ 1280      // persistent blocks (5/CU, 15 waves/CU)
#define EPS_ 1e-5f

// count[b] = clip(floor(lens*T)+1, 1, T); when length == 1.0 exactly the
// reference takes the FULL mean over T frames (the jnp.where branch).
static __device__ __forceinline__ int row_count(float lenfrac) {
    float length = lenfrac * (float)T_;
    if (length == 1.0f) return T_;
    int c = (int)floorf(length) + 1;
    if (c < 1) c = 1;
    if (c > T_) c = T_;
    return c;
}

// ---- Kernel I: reset the work-stealing counter (ws is poisoned each call) ----
__global__ void init_kernel(int* __restrict__ counter) {
    if (threadIdx.x == 0) *counter = GRID_P_;  // first GRID_P_ tasks taken statically
}

// ---- Kernel P: dynamic work-stealing partial sums over contiguous chunks ----
// Task t -> (s = t/64 chunk, b = t%64 row): frames [s*64, min(s*64+64, count)).
// s-major order => guaranteed-active low-s chunks issue first (longest-first).
// 192 threads, thread t = float4 column; iteration k reads the chunk's bytes
// [3k KB, 3k+3 KB) -> each task is one fully contiguous 192 KB stream.
// Inactive tasks write zero partials (required: ws poisoned) and cost ~nothing,
// so CUs that draw them immediately steal more work -> near-perfect balance.
// Partial[task] is a fixed-order sum -> bit-deterministic across replays.
__global__ __launch_bounds__(192) void partial_kernel(const float* __restrict__ outp,
                                                      const float* __restrict__ lens,
                                                      int* __restrict__ counter,
                                                      float* __restrict__ partial) {
    const int tid = threadIdx.x;  // 0..191
    __shared__ int s_task;
    int task = blockIdx.x;  // static first task: no atomic burst at t=0
    while (task < TASKS_) {
        const int b = task & (B_ - 1);
        const int s = task >> 6;  // TASKS_/B_ = 32 chunks, s-major decode
        const int tcount = row_count(lens[b]);
        const int t0 = s * CHUNK_;
        const int t1 = min(t0 + CHUNK_, tcount);

        const float4* base = (const float4*)(outp + (size_t)b * (T_ * D_)) + tid;
        float4 a0 = {0.f, 0.f, 0.f, 0.f}, a1 = a0, a2 = a0, a3 = a0;
        int t = t0;
        for (; t + 3 < t1; t += 4) {
            float4 v0 = base[(size_t)(t + 0) * D4_];
            float4 v1 = base[(size_t)(t + 1) * D4_];
            float4 v2 = base[(size_t)(t + 2) * D4_];
            float4 v3 = base[(size_t)(t + 3) * D4_];
            a0.x += v0.x; a0.y += v0.y; a0.z += v0.z; a0.w += v0.w;
            a1.x += v1.x; a1.y += v1.y; a1.z += v1.z; a1.w += v1.w;
            a2.x += v2.x; a2.y += v2.y; a2.z += v2.z; a2.w += v2.w;
            a3.x += v3.x; a3.y += v3.y; a3.z += v3.z; a3.w += v3.w;
        }
        for (; t < t1; ++t) {
            float4 v0 = base[(size_t)t * D4_];
            a0.x += v0.x; a0.y += v0.y; a0.z += v0.z; a0.w += v0.w;
        }
        float4 acc;
        acc.x = (a0.x + a1.x) + (a2.x + a3.x);
        acc.y = (a0.y + a1.y) + (a2.y + a3.y);
        acc.z = (a0.z + a1.z) + (a2.z + a3.z);
        acc.w = (a0.w + a1.w) + (a2.w + a3.w);
        ((float4*)partial)[((size_t)s * B_ + b) * D4_ + tid] = acc;

        // pop next task
        if (tid == 0) s_task = atomicAdd(counter, 1);
        __syncthreads();
        task = s_task;
        __syncthreads();  // all threads read s_task before tid0 can overwrite it
    }
}

// ---- Kernel F: fused {global min/max of gnoise} + {reduce NCHUNK_ partials}
//      + {divide by count} + {add scaled noise} -> out [B, D].
// 48 blocks x 256 threads = 12288 threads = exactly B*D/4 float4 outputs.
// Every block redundantly scans gnoise (192 KB, L2-resident) -- cheaper than
// a separate kernel + launch.
__global__ __launch_bounds__(256) void finalize_kernel(const float* __restrict__ lens,
                                                       const float* __restrict__ graw,
                                                       const float* __restrict__ partial,
                                                       float* __restrict__ outp) {
    const int tid = threadIdx.x;
    const int idx = blockIdx.x * 256 + tid;  // 0..12287, float4 index over [B, D]

    // --- block-redundant global min/max of gnoise_raw ---
    const float4* g4 = (const float4*)graw;
    float vmin = INFINITY, vmax = -INFINITY;
    for (int i = tid; i < B_ * D4_; i += 256) {  // 48 iters
        float4 v = g4[i];
        vmin = fminf(vmin, fminf(fminf(v.x, v.y), fminf(v.z, v.w)));
        vmax = fmaxf(vmax, fmaxf(fmaxf(v.x, v.y), fmaxf(v.z, v.w)));
    }
    #pragma unroll
    for (int off = 1; off < 64; off <<= 1) {
        vmin = fminf(vmin, __shfl_xor(vmin, off, 64));
        vmax = fmaxf(vmax, __shfl_xor(vmax, off, 64));
    }
    __shared__ float red[8];  // 4 waves: [0..3]=min, [4..7]=max
    const int wave = tid >> 6;
    if ((tid & 63) == 0) { red[wave] = vmin; red[4 + wave] = vmax; }
    __syncthreads();
    vmin = fminf(fminf(red[0], red[1]), fminf(red[2], red[3]));
    vmax = fmaxf(fmaxf(red[4], red[5]), fmaxf(red[6], red[7]));
    const float scale = 1.0f / (vmax - vmin);

    // --- sum the NCHUNK_ partials for this (b, c4) ---
    const int b = idx / D4_;
    const int c4 = idx - b * D4_;
    const float4* p4 = (const float4*)partial;
    float4 acc = {0.f, 0.f, 0.f, 0.f};
    #pragma unroll
    for (int s = 0; s < NCHUNK_; ++s) {
        float4 v = p4[((size_t)s * B_ + b) * D4_ + c4];
        acc.x += v.x; acc.y += v.y; acc.z += v.z; acc.w += v.w;
    }
    const float inv = 1.0f / (float)row_count(lens[b]);

    // gnoise = EPS * ((1-9)*g + 9), g normalized to [0,1]
    float4 g = g4[idx];
    float4 o;
    o.x = acc.x * inv + EPS_ * (9.0f - 8.0f * ((g.x - vmin) * scale));
    o.y = acc.y * inv + EPS_ * (9.0f - 8.0f * ((g.y - vmin) * scale));
    o.z = acc.z * inv + EPS_ * (9.0f - 8.0f * ((g.z - vmin) * scale));
    o.w = acc.w * inv + EPS_ * (9.0f - 8.0f * ((g.w - vmin) * scale));
    ((float4*)outp)[idx] = o;
}

extern "C" void kernel_launch(void* const* d_in, const int* in_sizes, int n_in,
                              void* d_out, int out_size, void* d_ws, size_t ws_size,
                              hipStream_t stream) {
    const float* outputs = (const float*)d_in[0];   // [B, T, D] fp32
    const float* lens    = (const float*)d_in[1];   // [B] fp32
    const float* graw    = (const float*)d_in[2];   // [B, D] fp32
    float* out = (float*)d_out;                     // [B, 1, D] fp32

    int*   counter = (int*)d_ws;                    // work-stealing counter
    float* partial = (float*)d_ws + 64;             // NCHUNK_*B_*D_ floats = 6.3 MB

    init_kernel<<<1, 64, 0, stream>>>(counter);
    partial_kernel<<<GRID_P_, 192, 0, stream>>>(outputs, lens, counter, partial);
    finalize_kernel<<<48, 256, 0, stream>>>(lens, graw, partial, out);
}